// Round 1
// baseline (903.071 us; speedup 1.0000x reference)
//
#include <hip/hip_runtime.h>
#include <cfloat>

#define N_NODES 50000
#define N_EDGES 800000
#define N_GRAPHS 64

// ---------------- CSR build ----------------

__global__ void hist_kernel(const int* __restrict__ dst, int* __restrict__ deg, int n) {
    int i = blockIdx.x * blockDim.x + threadIdx.x;
    if (i < n) atomicAdd(&deg[dst[i]], 1);
}

// Single-block run-based exclusive scan: thread t owns a contiguous run.
__global__ void scan_kernel(const int* __restrict__ deg, int* __restrict__ rowptr,
                            int* __restrict__ cursor, int n) {
    constexpr int T = 1024;
    __shared__ int sm[T];
    int t = threadIdx.x;
    int items = (n + T - 1) / T;
    int lo = t * items;
    int hi = lo + items; if (hi > n) hi = n;
    int s = 0;
    for (int i = lo; i < hi; ++i) s += deg[i];
    sm[t] = s;
    __syncthreads();
    for (int off = 1; off < T; off <<= 1) {
        int x = (t >= off) ? sm[t - off] : 0;
        __syncthreads();
        sm[t] += x;
        __syncthreads();
    }
    int run = sm[t] - s;  // exclusive prefix of this thread's run
    for (int i = lo; i < hi; ++i) {
        int d = deg[i];
        rowptr[i] = run;
        cursor[i] = run;
        run += d;
    }
    if (t == T - 1) rowptr[n] = run;
}

__global__ void scatter_kernel(const int* __restrict__ src, const int* __restrict__ dst,
                               int* __restrict__ cursor, int* __restrict__ csrc, int n) {
    int i = blockIdx.x * blockDim.x + threadIdx.x;
    if (i < n) {
        int d = dst[i];
        int p = atomicAdd(&cursor[d], 1);
        csrc[p] = src[i];
    }
}

// ---------------- graph boundaries (batch is sorted) ----------------

__global__ void start_init_kernel(int* __restrict__ start, int n) {
    int i = threadIdx.x;
    if (i <= N_GRAPHS) start[i] = n;
}

__global__ void boundary_kernel(const int* __restrict__ batch, int* __restrict__ start, int n) {
    int i = blockIdx.x * blockDim.x + threadIdx.x;
    if (i >= n) return;
    int b = batch[i];
    int pb = (i == 0) ? -1 : batch[i - 1];
    for (int g = pb + 1; g <= b; ++g) start[g] = i;
}

// ---------------- fused dual GEMM: xl = h@Wl, xr = h@Wr ----------------
// W staged in LDS as-is ([k][c]); x tile staged transposed ([k][row]).
// Each thread: 4 rows x 4 cols register tile, float4 LDS reads.

template<int DIN, int DOUT, int TR>
__global__ __launch_bounds__(256) void gemm2_kernel(const float* __restrict__ h,
        const float* __restrict__ Wl, const float* __restrict__ Wr,
        float* __restrict__ xl, float* __restrict__ xr, int n) {
    constexpr int CG = (2 * DOUT) / 4;   // col-groups (threads along cols)
    constexpr int RG = 256 / CG;         // row-groups
    static_assert(RG * 4 == TR, "tile rows mismatch");
    constexpr int TRP = TR + 4;          // padded (keeps 16B alignment, breaks bank stride)
    __shared__ float sW[2 * DIN * DOUT];
    __shared__ float sX[DIN * TRP];
    int tid = threadIdx.x;
    for (int i = tid; i < DIN * DOUT; i += 256) {
        sW[i] = Wl[i];
        sW[DIN * DOUT + i] = Wr[i];
    }
    int r0 = blockIdx.x * TR;
    for (int i = tid; i < TR * DIN; i += 256) {
        int row = i / DIN, k = i % DIN;
        float v = (r0 + row < n) ? h[(r0 + row) * DIN + k] : 0.f;
        sX[k * TRP + row] = v;
    }
    __syncthreads();

    int cg = tid % CG, rg = tid / CG;
    int c = cg * 4;
    int sel = (c >= DOUT) ? 1 : 0;
    int cc = c - sel * DOUT;
    const float* wp = sW + sel * DIN * DOUT + cc;
    const float* xp = sX + rg * 4;

    float acc[4][4] = {};
#pragma unroll 4
    for (int k = 0; k < DIN; ++k) {
        float4 wv = *(const float4*)(wp + k * DOUT);
        float4 xv = *(const float4*)(xp + k * TRP);
        float xa[4] = {xv.x, xv.y, xv.z, xv.w};
        float wa[4] = {wv.x, wv.y, wv.z, wv.w};
#pragma unroll
        for (int r = 0; r < 4; ++r)
#pragma unroll
            for (int q = 0; q < 4; ++q)
                acc[r][q] += xa[r] * wa[q];
    }

    float* obase = sel ? xr : xl;
#pragma unroll
    for (int r = 0; r < 4; ++r) {
        int row = r0 + rg * 4 + r;
        if (row < n) {
            float4 o = make_float4(acc[r][0], acc[r][1], acc[r][2], acc[r][3]);
            *(float4*)(obase + row * DOUT + cc) = o;
        }
    }
}

// ---------------- fused per-node GATv2 softmax-aggregate (online softmax) ----------------

template<int DOUT, bool LEAKY>
__global__ __launch_bounds__(256) void edge_kernel(
        const float* __restrict__ xl, const float* __restrict__ xr,
        const float* __restrict__ avec, const float* __restrict__ bias,
        const int* __restrict__ rowptr, const int* __restrict__ csrc,
        float* __restrict__ out, int n) {
    constexpr int LANES = (DOUT < 64) ? DOUT : 64;  // lanes per node group
    constexpr int DPL = (DOUT + 63) / 64;           // dims per lane (1 or 2)
    constexpr int NPW = 64 / LANES;                 // nodes per wave
    int wid = (blockIdx.x * blockDim.x + threadIdx.x) >> 6;
    int lane = threadIdx.x & 63;
    int group = lane / LANES;
    int gl = lane % LANES;
    int node = wid * NPW + group;
    if (node >= n) return;

    float xrv[DPL], av[DPL], acc[DPL];
#pragma unroll
    for (int d = 0; d < DPL; ++d) {
        xrv[d] = xr[node * DOUT + gl + d * LANES];
        av[d] = avec[gl + d * LANES];
        acc[d] = 0.f;
    }
    float m = -FLT_MAX, denom = 0.f;
    int e0 = rowptr[node], e1 = rowptr[node + 1];
    for (int p = e0; p < e1; ++p) {
        int s = csrc[p];
        float xlv[DPL];
        float part = 0.f;
#pragma unroll
        for (int d = 0; d < DPL; ++d) {
            xlv[d] = xl[s * DOUT + gl + d * LANES];
            float t = xlv[d] + xrv[d];
            t = (t > 0.f) ? t : 0.2f * t;
            part += t * av[d];
        }
#pragma unroll
        for (int mask = LANES / 2; mask >= 1; mask >>= 1)
            part += __shfl_xor(part, mask, 64);
        float e = part;
        if (e > m) {
            float sc = expf(m - e);
            denom *= sc;
#pragma unroll
            for (int d = 0; d < DPL; ++d) acc[d] *= sc;
            m = e;
        }
        float w = expf(e - m);
        denom += w;
#pragma unroll
        for (int d = 0; d < DPL; ++d) acc[d] += w * xlv[d];
    }
    float inv = 1.f / (denom + 1e-16f);
#pragma unroll
    for (int d = 0; d < DPL; ++d) {
        float o = acc[d] * inv + bias[gl + d * LANES];
        if (LEAKY) o = (o > 0.f) ? o : 0.01f * o;
        out[node * DOUT + gl + d * LANES] = o;
    }
}

// ---------------- global max pool (per sorted-batch graph) ----------------

__global__ void pool_kernel(const float* __restrict__ h, const int* __restrict__ start,
                            float* __restrict__ gout) {
    int g = blockIdx.x;
    int d = threadIdx.x;  // 128
    int s0 = start[g], s1 = start[g + 1];
    float v = -FLT_MAX;
    for (int nn = s0; nn < s1; ++nn)
        v = fmaxf(v, h[nn * 128 + d]);
    gout[g * 128 + d] = v;
}

// ---------------- fused MLP head ----------------

__global__ __launch_bounds__(256) void mlp_kernel(const float* __restrict__ gpool,
        const float* __restrict__ w1, const float* __restrict__ b1,
        const float* __restrict__ w2, const float* __restrict__ b2,
        const float* __restrict__ w3, const float* __restrict__ b3,
        const float* __restrict__ w4, const float* __restrict__ b4,
        const float* __restrict__ w5, const float* __restrict__ b5,
        float* __restrict__ out) {
    __shared__ float A[1024], B[1024];
    int r = blockIdx.x, t = threadIdx.x;
    if (t < 128) A[t] = gpool[r * 128 + t];
    __syncthreads();
    for (int c = t; c < 1024; c += 256) {
        float acc = b1[c];
        for (int k = 0; k < 128; ++k) acc += A[k] * w1[k * 1024 + c];
        B[c] = fmaxf(acc, 0.f);
    }
    __syncthreads();
    for (int c = t; c < 512; c += 256) {
        float acc = b2[c];
        for (int k = 0; k < 1024; ++k) acc += B[k] * w2[k * 512 + c];
        A[c] = fmaxf(acc, 0.f);
    }
    __syncthreads();
    if (t < 128) {
        float acc = b3[t];
        for (int k = 0; k < 512; ++k) acc += A[k] * w3[k * 128 + t];
        B[t] = fmaxf(acc, 0.f);
    }
    __syncthreads();
    if (t < 32) {
        float acc = b4[t];
        for (int k = 0; k < 128; ++k) acc += B[k] * w4[k * 32 + t];
        A[t] = fmaxf(acc, 0.f);
    }
    __syncthreads();
    if (t < 4) {
        float acc = b5[t];
        for (int k = 0; k < 32; ++k) acc += A[k] * w5[k * 4 + t];
        out[r * 4 + t] = acc;
    }
}

// ---------------- host launch ----------------

extern "C" void kernel_launch(void* const* d_in, const int* in_sizes, int n_in,
                              void* d_out, int out_size, void* d_ws, size_t ws_size,
                              hipStream_t stream) {
    const float* x     = (const float*)d_in[0];
    const int*   ei    = (const int*)d_in[1];
    const int*   batch = (const int*)d_in[2];
    const int*   src   = ei;
    const int*   dst   = ei + N_EDGES;
    const float* Wl1 = (const float*)d_in[3];
    const float* Wr1 = (const float*)d_in[4];
    const float* a1  = (const float*)d_in[5];
    const float* b1  = (const float*)d_in[6];
    const float* Wl2 = (const float*)d_in[7];
    const float* Wr2 = (const float*)d_in[8];
    const float* a2  = (const float*)d_in[9];
    const float* b2  = (const float*)d_in[10];
    const float* Wl3 = (const float*)d_in[11];
    const float* Wr3 = (const float*)d_in[12];
    const float* a3  = (const float*)d_in[13];
    const float* b3  = (const float*)d_in[14];
    const float* mw1 = (const float*)d_in[15];
    const float* mb1 = (const float*)d_in[16];
    const float* mw2 = (const float*)d_in[17];
    const float* mb2 = (const float*)d_in[18];
    const float* mw3 = (const float*)d_in[19];
    const float* mb3 = (const float*)d_in[20];
    const float* mw4 = (const float*)d_in[21];
    const float* mb4 = (const float*)d_in[22];
    const float* mw5 = (const float*)d_in[23];
    const float* mb5 = (const float*)d_in[24];

    char* ws = (char*)d_ws;
    size_t off = 0;
    auto alloc = [&](size_t bytes) -> void* {
        void* p = ws + off;
        off = (off + bytes + 255) & ~(size_t)255;
        return p;
    };
    int*   deg    = (int*)alloc(N_NODES * 4);
    int*   rowptr = (int*)alloc((N_NODES + 1) * 4);
    int*   cursor = (int*)alloc(N_NODES * 4);
    int*   csrc   = (int*)alloc(N_EDGES * 4);
    float* xl     = (float*)alloc((size_t)N_NODES * 128 * 4);
    float* xr     = (float*)alloc((size_t)N_NODES * 128 * 4);
    float* hA     = (float*)alloc((size_t)N_NODES * 128 * 4);
    float* hB     = (float*)alloc((size_t)N_NODES * 128 * 4);
    int*   start  = (int*)alloc((N_GRAPHS + 1) * 4);
    float* pool   = (float*)alloc(N_GRAPHS * 128 * 4);

    hipMemsetAsync(deg, 0, N_NODES * 4, stream);
    hist_kernel<<<(N_EDGES + 255) / 256, 256, 0, stream>>>(dst, deg, N_EDGES);
    scan_kernel<<<1, 1024, 0, stream>>>(deg, rowptr, cursor, N_NODES);
    scatter_kernel<<<(N_EDGES + 255) / 256, 256, 0, stream>>>(src, dst, cursor, csrc, N_EDGES);
    start_init_kernel<<<1, 128, 0, stream>>>(start, N_NODES);
    boundary_kernel<<<(N_NODES + 255) / 256, 256, 0, stream>>>(batch, start, N_NODES);

    // Layer 1: 128 -> 32
    gemm2_kernel<128, 32, 64><<<(N_NODES + 63) / 64, 256, 0, stream>>>(x, Wl1, Wr1, xl, xr, N_NODES);
    {
        int waves = (N_NODES + 1) / 2;           // 2 nodes per wave
        edge_kernel<32, true><<<(waves + 3) / 4, 256, 0, stream>>>(xl, xr, a1, b1, rowptr, csrc, hB, N_NODES);
    }
    // Layer 2: 32 -> 64
    gemm2_kernel<32, 64, 32><<<(N_NODES + 31) / 32, 256, 0, stream>>>(hB, Wl2, Wr2, xl, xr, N_NODES);
    edge_kernel<64, true><<<(N_NODES + 3) / 4, 256, 0, stream>>>(xl, xr, a2, b2, rowptr, csrc, hA, N_NODES);
    // Layer 3: 64 -> 128
    gemm2_kernel<64, 128, 16><<<(N_NODES + 15) / 16, 256, 0, stream>>>(hA, Wl3, Wr3, xl, xr, N_NODES);
    edge_kernel<128, false><<<(N_NODES + 3) / 4, 256, 0, stream>>>(xl, xr, a3, b3, rowptr, csrc, hB, N_NODES);

    pool_kernel<<<N_GRAPHS, 128, 0, stream>>>(hB, start, pool);
    mlp_kernel<<<N_GRAPHS, 256, 0, stream>>>(pool, mw1, mb1, mw2, mb2, mw3, mb3, mw4, mb4, mw5, mb5,
                                             (float*)d_out);
}

// Round 2
// 784.810 us; speedup vs baseline: 1.1507x; 1.1507x over previous
//
#include <hip/hip_runtime.h>
#include <cfloat>

#define N_NODES 50000
#define N_EDGES 800000
#define N_GRAPHS 64
#define POOL_CHUNK 64

// ---------------- CSR build ----------------

__global__ void hist_kernel(const int* __restrict__ dst, int* __restrict__ deg, int n) {
    int i = blockIdx.x * blockDim.x + threadIdx.x;
    if (i < n) atomicAdd(&deg[dst[i]], 1);
}

// Single-block run-based exclusive scan: thread t owns a contiguous run.
__global__ void scan_kernel(const int* __restrict__ deg, int* __restrict__ rowptr,
                            int* __restrict__ cursor, int n) {
    constexpr int T = 1024;
    __shared__ int sm[T];
    int t = threadIdx.x;
    int items = (n + T - 1) / T;
    int lo = t * items;
    int hi = lo + items; if (hi > n) hi = n;
    int s = 0;
    for (int i = lo; i < hi; ++i) s += deg[i];
    sm[t] = s;
    __syncthreads();
    for (int off = 1; off < T; off <<= 1) {
        int x = (t >= off) ? sm[t - off] : 0;
        __syncthreads();
        sm[t] += x;
        __syncthreads();
    }
    int run = sm[t] - s;  // exclusive prefix of this thread's run
    for (int i = lo; i < hi; ++i) {
        int d = deg[i];
        rowptr[i] = run;
        cursor[i] = run;
        run += d;
    }
    if (t == T - 1) rowptr[n] = run;
}

__global__ void scatter_kernel(const int* __restrict__ src, const int* __restrict__ dst,
                               int* __restrict__ cursor, int* __restrict__ csrc, int n) {
    int i = blockIdx.x * blockDim.x + threadIdx.x;
    if (i < n) {
        int d = dst[i];
        int p = atomicAdd(&cursor[d], 1);
        csrc[p] = src[i];
    }
}

// ---------------- fused dual GEMM: xl = h@Wl, xr = h@Wr ----------------

template<int DIN, int DOUT, int TR>
__global__ __launch_bounds__(256) void gemm2_kernel(const float* __restrict__ h,
        const float* __restrict__ Wl, const float* __restrict__ Wr,
        float* __restrict__ xl, float* __restrict__ xr, int n) {
    constexpr int CG = (2 * DOUT) / 4;   // col-groups (threads along cols)
    constexpr int RG = 256 / CG;         // row-groups
    static_assert(RG * 4 == TR, "tile rows mismatch");
    constexpr int TRP = TR + 4;          // padded (keeps 16B alignment, breaks bank stride)
    __shared__ float sW[2 * DIN * DOUT];
    __shared__ float sX[DIN * TRP];
    int tid = threadIdx.x;
    for (int i = tid; i < DIN * DOUT; i += 256) {
        sW[i] = Wl[i];
        sW[DIN * DOUT + i] = Wr[i];
    }
    int r0 = blockIdx.x * TR;
    for (int i = tid; i < TR * DIN; i += 256) {
        int row = i / DIN, k = i % DIN;
        float v = (r0 + row < n) ? h[(r0 + row) * DIN + k] : 0.f;
        sX[k * TRP + row] = v;
    }
    __syncthreads();

    int cg = tid % CG, rg = tid / CG;
    int c = cg * 4;
    int sel = (c >= DOUT) ? 1 : 0;
    int cc = c - sel * DOUT;
    const float* wp = sW + sel * DIN * DOUT + cc;
    const float* xp = sX + rg * 4;

    float acc[4][4] = {};
#pragma unroll 4
    for (int k = 0; k < DIN; ++k) {
        float4 wv = *(const float4*)(wp + k * DOUT);
        float4 xv = *(const float4*)(xp + k * TRP);
        float xa[4] = {xv.x, xv.y, xv.z, xv.w};
        float wa[4] = {wv.x, wv.y, wv.z, wv.w};
#pragma unroll
        for (int r = 0; r < 4; ++r)
#pragma unroll
            for (int q = 0; q < 4; ++q)
                acc[r][q] += xa[r] * wa[q];
    }

    float* obase = sel ? xr : xl;
#pragma unroll
    for (int r = 0; r < 4; ++r) {
        int row = r0 + rg * 4 + r;
        if (row < n) {
            float4 o = make_float4(acc[r][0], acc[r][1], acc[r][2], acc[r][3]);
            *(float4*)(obase + row * DOUT + cc) = o;
        }
    }
}

// ---------------- fused per-node GATv2 softmax-aggregate (online softmax) ----------------

template<int DOUT, bool LEAKY>
__global__ __launch_bounds__(256) void edge_kernel(
        const float* __restrict__ xl, const float* __restrict__ xr,
        const float* __restrict__ avec, const float* __restrict__ bias,
        const int* __restrict__ rowptr, const int* __restrict__ csrc,
        float* __restrict__ out, int n) {
    constexpr int LANES = (DOUT < 64) ? DOUT : 64;  // lanes per node group
    constexpr int DPL = (DOUT + 63) / 64;           // dims per lane (1 or 2)
    constexpr int NPW = 64 / LANES;                 // nodes per wave
    int wid = (blockIdx.x * blockDim.x + threadIdx.x) >> 6;
    int lane = threadIdx.x & 63;
    int group = lane / LANES;
    int gl = lane % LANES;
    int node = wid * NPW + group;
    if (node >= n) return;

    float xrv[DPL], av[DPL], acc[DPL];
#pragma unroll
    for (int d = 0; d < DPL; ++d) {
        xrv[d] = xr[node * DOUT + gl + d * LANES];
        av[d] = avec[gl + d * LANES];
        acc[d] = 0.f;
    }
    float m = -FLT_MAX, denom = 0.f;
    int e0 = rowptr[node], e1 = rowptr[node + 1];
    for (int p = e0; p < e1; ++p) {
        int s = csrc[p];
        float xlv[DPL];
        float part = 0.f;
#pragma unroll
        for (int d = 0; d < DPL; ++d) {
            xlv[d] = xl[s * DOUT + gl + d * LANES];
            float t = xlv[d] + xrv[d];
            t = (t > 0.f) ? t : 0.2f * t;
            part += t * av[d];
        }
#pragma unroll
        for (int mask = LANES / 2; mask >= 1; mask >>= 1)
            part += __shfl_xor(part, mask, 64);
        float e = part;
        if (e > m) {
            float sc = expf(m - e);
            denom *= sc;
#pragma unroll
            for (int d = 0; d < DPL; ++d) acc[d] *= sc;
            m = e;
        }
        float w = expf(e - m);
        denom += w;
#pragma unroll
        for (int d = 0; d < DPL; ++d) acc[d] += w * xlv[d];
    }
    float inv = 1.f / (denom + 1e-16f);
#pragma unroll
    for (int d = 0; d < DPL; ++d) {
        float o = acc[d] * inv + bias[gl + d * LANES];
        if (LEAKY) o = (o > 0.f) ? o : 0.01f * o;
        out[node * DOUT + gl + d * LANES] = o;
    }
}

// ---------------- global max pool (node-parallel, atomicMax on encoded uint) ----------------

__device__ __forceinline__ unsigned int enc_f32(float f) {
    unsigned int b = __float_as_uint(f);
    return (b & 0x80000000u) ? ~b : (b | 0x80000000u);
}
__device__ __forceinline__ float dec_f32(unsigned int u) {
    unsigned int b = (u & 0x80000000u) ? (u ^ 0x80000000u) : ~u;
    return __uint_as_float(b);
}

__global__ __launch_bounds__(128) void pool_kernel(const float* __restrict__ h,
        const int* __restrict__ batch, unsigned int* __restrict__ gout, int n) {
    int c0 = blockIdx.x * POOL_CHUNK;
    if (c0 >= n) return;
    int end = c0 + POOL_CHUNK; if (end > n) end = n;
    int d = threadIdx.x;  // 128
    float run = -FLT_MAX;
    int gcur = batch[c0];
    for (int nn = c0; nn < end; ++nn) {
        int g = batch[nn];
        if (g != gcur) {                       // wave-uniform branch
            atomicMax(&gout[gcur * 128 + d], enc_f32(run));
            run = -FLT_MAX;
            gcur = g;
        }
        run = fmaxf(run, h[nn * 128 + d]);
    }
    atomicMax(&gout[gcur * 128 + d], enc_f32(run));
}

// ---------------- fused MLP head ----------------

__global__ __launch_bounds__(256) void mlp_kernel(const unsigned int* __restrict__ gpool,
        const float* __restrict__ w1, const float* __restrict__ b1,
        const float* __restrict__ w2, const float* __restrict__ b2,
        const float* __restrict__ w3, const float* __restrict__ b3,
        const float* __restrict__ w4, const float* __restrict__ b4,
        const float* __restrict__ w5, const float* __restrict__ b5,
        float* __restrict__ out) {
    __shared__ float A[1024], B[1024];
    int r = blockIdx.x, t = threadIdx.x;
    if (t < 128) A[t] = dec_f32(gpool[r * 128 + t]);
    __syncthreads();
    for (int c = t; c < 1024; c += 256) {
        float acc = b1[c];
        for (int k = 0; k < 128; ++k) acc += A[k] * w1[k * 1024 + c];
        B[c] = fmaxf(acc, 0.f);
    }
    __syncthreads();
    for (int c = t; c < 512; c += 256) {
        float acc = b2[c];
        for (int k = 0; k < 1024; ++k) acc += B[k] * w2[k * 512 + c];
        A[c] = fmaxf(acc, 0.f);
    }
    __syncthreads();
    if (t < 128) {
        float acc = b3[t];
        for (int k = 0; k < 512; ++k) acc += A[k] * w3[k * 128 + t];
        B[t] = fmaxf(acc, 0.f);
    }
    __syncthreads();
    if (t < 32) {
        float acc = b4[t];
        for (int k = 0; k < 128; ++k) acc += B[k] * w4[k * 32 + t];
        A[t] = fmaxf(acc, 0.f);
    }
    __syncthreads();
    if (t < 4) {
        float acc = b5[t];
        for (int k = 0; k < 32; ++k) acc += A[k] * w5[k * 4 + t];
        out[r * 4 + t] = acc;
    }
}

// ---------------- host launch ----------------

extern "C" void kernel_launch(void* const* d_in, const int* in_sizes, int n_in,
                              void* d_out, int out_size, void* d_ws, size_t ws_size,
                              hipStream_t stream) {
    const float* x     = (const float*)d_in[0];
    const int*   ei    = (const int*)d_in[1];
    const int*   batch = (const int*)d_in[2];
    const int*   src   = ei;
    const int*   dst   = ei + N_EDGES;
    const float* Wl1 = (const float*)d_in[3];
    const float* Wr1 = (const float*)d_in[4];
    const float* a1  = (const float*)d_in[5];
    const float* b1  = (const float*)d_in[6];
    const float* Wl2 = (const float*)d_in[7];
    const float* Wr2 = (const float*)d_in[8];
    const float* a2  = (const float*)d_in[9];
    const float* b2  = (const float*)d_in[10];
    const float* Wl3 = (const float*)d_in[11];
    const float* Wr3 = (const float*)d_in[12];
    const float* a3  = (const float*)d_in[13];
    const float* b3  = (const float*)d_in[14];
    const float* mw1 = (const float*)d_in[15];
    const float* mb1 = (const float*)d_in[16];
    const float* mw2 = (const float*)d_in[17];
    const float* mb2 = (const float*)d_in[18];
    const float* mw3 = (const float*)d_in[19];
    const float* mb3 = (const float*)d_in[20];
    const float* mw4 = (const float*)d_in[21];
    const float* mb4 = (const float*)d_in[22];
    const float* mw5 = (const float*)d_in[23];
    const float* mb5 = (const float*)d_in[24];

    char* ws = (char*)d_ws;
    size_t off = 0;
    auto alloc = [&](size_t bytes) -> void* {
        void* p = ws + off;
        off = (off + bytes + 255) & ~(size_t)255;
        return p;
    };
    int*   deg    = (int*)alloc(N_NODES * 4);
    int*   rowptr = (int*)alloc((N_NODES + 1) * 4);
    int*   cursor = (int*)alloc(N_NODES * 4);
    int*   csrc   = (int*)alloc(N_EDGES * 4);
    float* xl     = (float*)alloc((size_t)N_NODES * 128 * 4);
    float* xr     = (float*)alloc((size_t)N_NODES * 128 * 4);
    float* hA     = (float*)alloc((size_t)N_NODES * 128 * 4);
    float* hB     = (float*)alloc((size_t)N_NODES * 128 * 4);
    unsigned int* pool = (unsigned int*)alloc(N_GRAPHS * 128 * 4);

    hipMemsetAsync(deg, 0, N_NODES * 4, stream);
    hipMemsetAsync(pool, 0, N_GRAPHS * 128 * 4, stream);  // 0 == encoded -inf
    hist_kernel<<<(N_EDGES + 255) / 256, 256, 0, stream>>>(dst, deg, N_EDGES);
    scan_kernel<<<1, 1024, 0, stream>>>(deg, rowptr, cursor, N_NODES);
    scatter_kernel<<<(N_EDGES + 255) / 256, 256, 0, stream>>>(src, dst, cursor, csrc, N_EDGES);

    // Layer 1: 128 -> 32
    gemm2_kernel<128, 32, 64><<<(N_NODES + 63) / 64, 256, 0, stream>>>(x, Wl1, Wr1, xl, xr, N_NODES);
    {
        int waves = (N_NODES + 1) / 2;           // 2 nodes per wave
        edge_kernel<32, true><<<(waves + 3) / 4, 256, 0, stream>>>(xl, xr, a1, b1, rowptr, csrc, hB, N_NODES);
    }
    // Layer 2: 32 -> 64
    gemm2_kernel<32, 64, 32><<<(N_NODES + 31) / 32, 256, 0, stream>>>(hB, Wl2, Wr2, xl, xr, N_NODES);
    edge_kernel<64, true><<<(N_NODES + 3) / 4, 256, 0, stream>>>(xl, xr, a2, b2, rowptr, csrc, hA, N_NODES);
    // Layer 3: 64 -> 128
    gemm2_kernel<64, 128, 16><<<(N_NODES + 15) / 16, 256, 0, stream>>>(hA, Wl3, Wr3, xl, xr, N_NODES);
    edge_kernel<128, false><<<(N_NODES + 3) / 4, 256, 0, stream>>>(xl, xr, a3, b3, rowptr, csrc, hB, N_NODES);

    pool_kernel<<<(N_NODES + POOL_CHUNK - 1) / POOL_CHUNK, 128, 0, stream>>>(hB, batch, pool, N_NODES);
    mlp_kernel<<<N_GRAPHS, 256, 0, stream>>>(pool, mw1, mb1, mw2, mb2, mw3, mb3, mw4, mb4, mw5, mb5,
                                             (float*)d_out);
}